// Round 6
// baseline (112.830 us; speedup 1.0000x reference)
//
#include <hip/hip_runtime.h>
#include <hip/hip_bf16.h>

#define NB 4096
#define ND 512

typedef int i32x4 __attribute__((ext_vector_type(4)));
typedef int i32x8 __attribute__((ext_vector_type(8)));
typedef float f32x4 __attribute__((ext_vector_type(4)));

#define AS1 __attribute__((address_space(1)))
#define AS3 __attribute__((address_space(3)))

// ---- f32 -> fp8 e4m3fn (OCP), RNE, |x| <= 1 ----
__device__ __forceinline__ unsigned int f2e4m3(float x) {
    float a = fabsf(x);
    unsigned s = (__float_as_uint(x) >> 24) & 0x80u;
    if (a < 0.015625f) {                       // denorm/zero: step 2^-9
        int q = __float2int_rn(a * 512.0f);    // 0..8 (8 -> 0x08 == 2^-6)
        return s | (unsigned)q;
    }
    unsigned u = __float_as_uint(a);
    u += 0x7FFFFu + ((u >> 20) & 1u);          // RNE to 3-bit mantissa
    unsigned e8 = (u >> 23) - 120u;            // 1..7 for a in [2^-6, 1]
    unsigned m = (u >> 20) & 7u;
    return s | (e8 << 3) | m;
}

// ---------------- normalize + cast to fp8 (wave per row) + zero-init sums ----------------
__global__ __launch_bounds__(256) void nrm_kernel(
    const float* __restrict__ z0, const float* __restrict__ z1,
    const float* __restrict__ z2, unsigned char* __restrict__ nrm8,
    float* __restrict__ rowsum, float* __restrict__ colsum)
{
    const int w = threadIdx.x >> 6, lane = threadIdx.x & 63;
    const int row = blockIdx.x * 4 + w;
    const int p = blockIdx.y;
    if (lane == 0) {
        rowsum[p * NB + row] = 0.f;
        colsum[p * NB + row] = 0.f;
    }
    const float* z = (p == 0) ? z0 : (p == 1) ? z1 : z2;
    const float4* zr = (const float4*)(z + (size_t)row * ND);
    const float4 a = zr[lane * 2], b = zr[lane * 2 + 1];
    float ss = a.x * a.x + a.y * a.y + a.z * a.z + a.w * a.w
             + b.x * b.x + b.y * b.y + b.z * b.z + b.w * b.w;
    #pragma unroll
    for (int m = 32; m >= 1; m >>= 1) ss += __shfl_xor(ss, m);
    const float inv = 1.0f / fmaxf(sqrtf(ss), 1e-8f);
    uint2 o;
    o.x = f2e4m3(a.x * inv) | (f2e4m3(a.y * inv) << 8)
        | (f2e4m3(a.z * inv) << 16) | (f2e4m3(a.w * inv) << 24);
    o.y = f2e4m3(b.x * inv) | (f2e4m3(b.y * inv) << 8)
        | (f2e4m3(b.z * inv) << 16) | (f2e4m3(b.w * inv) << 24);
    *(uint2*)(nrm8 + ((size_t)p * NB + row) * ND + lane * 8) = o;
}

// ---------------- fused pair GEMM, MX-fp8: 256x256 tile, BK=128, 8 waves ----------------
// 4 K-tiles; 2 phases/K-tile (16 MFMA each, m201 template); A x3 + B x2 LDS
// buffers = 160 KB; counted vmcnt(4) once per tile; unit E8M0 scales (0x7F).
__global__ __launch_bounds__(512, 2) void pair_gemm_kernel(
    const unsigned char* __restrict__ nrm8,
    float* __restrict__ rowsum, float* __restrict__ colsum,
    float* __restrict__ diag)
{
    // XCD chunking: per pair, each XCD owns an 8by x 4bx chunk (WS ~1.5 MB < 4 MB L2)
    const int bid = blockIdx.x;
    const int xcd = bid & 7;
    const int rank = bid >> 3;
    const int p = rank >> 5;
    const int r2 = rank & 31;
    const int by = (xcd & 1) * 8 + (r2 >> 2);
    const int bx = (xcd >> 1) * 4 + (r2 & 3);
    const int ia = (p == 2) ? 1 : 0;
    const int ib = (p == 0) ? 1 : 2;

    const char* Aglob = (const char*)nrm8 + ((size_t)ia * NB + (size_t)by * 256) * ND;
    const char* Bglob = (const char*)nrm8 + ((size_t)ib * NB + (size_t)bx * 256) * ND;

    __shared__ char lds[163840];  // A: 3 x 32KB at 0; B: 2 x 32KB at 98304

    const int tid = threadIdx.x;
    const int lane = tid & 63;
    const int w = tid >> 6;
    const int wr = w >> 2, wc = w & 3;   // 2M x 4N; wave tile 128x64
    const int lr = lane & 15, lg = lane >> 4;

    // staging: op-tile = 256 rows x 128 B = 2048 chunks of 16B; 4 per thread.
    // row r = c>>3, phys slot qp = c&7 holds logical qp^(r&7) -> inverse-swizzled
    // SOURCE (rule 21), LDS dest linear. Source row stride = ND bytes.
    int srcOff[4];
    #pragma unroll
    for (int q = 0; q < 4; ++q) {
        const int c = q * 512 + tid;
        const int r = c >> 3;
        const int ql = (c & 7) ^ (r & 7);
        srcOff[q] = r * ND + ql * 16;
    }

    // frag reads: lane-group lg covers logical k-bytes [32lg, 32lg+32) = slots
    // {2lg, 2lg+1}; phys slot = logical ^ (lr&7). Same map for A and B, so any
    // HW-internal k permutation cancels in the contraction.
    const int s0 = ((2 * lg) ^ (lr & 7)) * 16;
    const int s1 = ((2 * lg + 1) ^ (lr & 7)) * 16;
    const int arow = (wr * 128 + lr) * 128;
    const int brow = (wc * 64 + lr) * 128;

    f32x4 acc[8][4] = {};

    #define STAGE(glob, tt, dstbase) do {                                           \
        _Pragma("unroll")                                                           \
        for (int q = 0; q < 4; ++q)                                                 \
            __builtin_amdgcn_global_load_lds(                                       \
                (const AS1 void*)((glob) + srcOff[q] + (tt) * 128),                 \
                (AS3 void*)(lds + (dstbase) + q * 8192 + w * 1024), 16, 0, 0);      \
    } while (0)

    #define LDF(dst, buf, rowbase, idx) do {                                        \
        i32x4 lo_ = *(const i32x4*)((buf) + (rowbase) + (idx) * 2048 + s0);         \
        i32x4 hi_ = *(const i32x4*)((buf) + (rowbase) + (idx) * 2048 + s1);         \
        dst = __builtin_shufflevector(lo_, hi_, 0, 1, 2, 3, 4, 5, 6, 7);            \
    } while (0)

    #define SC 0x7F7F7F7F

    // prologue: A(0), B(0), A(1); drain A(0)+B(0), keep A(1) in flight
    STAGE(Aglob, 0, 0);
    STAGE(Bglob, 0, 98304);
    STAGE(Aglob, 1, 32768);
    asm volatile("s_waitcnt vmcnt(4)" ::: "memory");
    __builtin_amdgcn_s_barrier();

    #pragma unroll
    for (int t = 0; t < 4; ++t) {
        const char* abuf = lds + (t % 3) * 32768;
        const char* bbuf = lds + 98304 + (t & 1) * 32768;
        const int bbn = 98304 + ((t + 1) & 1) * 32768;
        const int ab2 = ((t + 2) % 3) * 32768;

        i32x8 af[4], bfr[4];

        // ---------- phase 0: m0-3 x n0-3 ----------
        #pragma unroll
        for (int m = 0; m < 4; ++m) LDF(af[m], abuf, arow, m);
        #pragma unroll
        for (int n = 0; n < 4; ++n) LDF(bfr[n], bbuf, brow, n);
        if (t < 3) STAGE(Bglob, t + 1, bbn);
        __builtin_amdgcn_s_barrier();
        asm volatile("s_waitcnt lgkmcnt(0)" ::: "memory");
        __builtin_amdgcn_sched_barrier(0);
        __builtin_amdgcn_s_setprio(1);
        #pragma unroll
        for (int m = 0; m < 4; ++m)
            #pragma unroll
            for (int n = 0; n < 4; ++n)
                acc[m][n] = __builtin_amdgcn_mfma_scale_f32_16x16x128_f8f6f4(
                    af[m], bfr[n], acc[m][n], 0, 0, 0, SC, 0, SC);
        __builtin_amdgcn_s_setprio(0);
        __builtin_amdgcn_s_barrier();

        // ---------- phase 1: m4-7 x n0-3 (+ per-tile gate) ----------
        #pragma unroll
        for (int m = 0; m < 4; ++m) LDF(af[m], abuf, arow, m + 4);
        if (t < 2) STAGE(Aglob, t + 2, ab2);
        __builtin_amdgcn_s_barrier();
        asm volatile("s_waitcnt lgkmcnt(0)" ::: "memory");
        __builtin_amdgcn_sched_barrier(0);
        __builtin_amdgcn_s_setprio(1);
        #pragma unroll
        for (int m = 0; m < 4; ++m)
            #pragma unroll
            for (int n = 0; n < 4; ++n)
                acc[m + 4][n] = __builtin_amdgcn_mfma_scale_f32_16x16x128_f8f6f4(
                    af[m], bfr[n], acc[m + 4][n], 0, 0, 0, SC, 0, SC);
        __builtin_amdgcn_s_setprio(0);
        // gate: drain A(t+1)+B(t+1); leave A(t+2) in flight
        if (t < 2)       asm volatile("s_waitcnt vmcnt(4)" ::: "memory");
        else if (t == 2) asm volatile("s_waitcnt vmcnt(0)" ::: "memory");
        __builtin_amdgcn_s_barrier();
    }
    #undef STAGE
    #undef LDF

    // ---- diag (pre-exp): C frag row = lg*4+j (within 16), col = lr ----
    if (bx == by) {
        #pragma unroll
        for (int m = 0; m < 8; ++m)
            #pragma unroll
            for (int n = 0; n < 4; ++n)
                #pragma unroll
                for (int j = 0; j < 4; ++j) {
                    const int r = wr * 128 + m * 16 + lg * 4 + j;
                    const int c = wc * 64 + n * 16 + lr;
                    if (r == c) diag[p * NB + by * 256 + r] = acc[m][n][j];
                }
    }

    // ---- epilogue: e = exp2(sim*10*log2e - 10*log2e), row/col partials ----
    constexpr float C10 = 14.42695040888963f;
    float rs[8][4];
    float cs[4] = {0.f, 0.f, 0.f, 0.f};
    #pragma unroll
    for (int m = 0; m < 8; ++m)
        #pragma unroll
        for (int j = 0; j < 4; ++j) rs[m][j] = 0.f;

    #pragma unroll
    for (int m = 0; m < 8; ++m)
        #pragma unroll
        for (int n = 0; n < 4; ++n)
            #pragma unroll
            for (int j = 0; j < 4; ++j) {
                float e = exp2f(fmaf(acc[m][n][j], C10, -C10));
                rs[m][j] += e;
                cs[n] += e;
            }

    #pragma unroll
    for (int m = 0; m < 8; ++m)
        #pragma unroll
        for (int j = 0; j < 4; ++j) {
            float v = rs[m][j];
            v += __shfl_xor(v, 1);
            v += __shfl_xor(v, 2);
            v += __shfl_xor(v, 4);
            v += __shfl_xor(v, 8);
            rs[m][j] = v;
        }
    #pragma unroll
    for (int n = 0; n < 4; ++n) {
        float v = cs[n];
        v += __shfl_xor(v, 16);
        v += __shfl_xor(v, 32);
        cs[n] = v;
    }

    float* rowp = rowsum + p * NB + by * 256 + wr * 128;
    float* colp = colsum + p * NB + bx * 256 + wc * 64;
    if (lr == 0) {
        #pragma unroll
        for (int m = 0; m < 8; ++m)
            #pragma unroll
            for (int j = 0; j < 4; ++j)
                atomicAdd(&rowp[m * 16 + lg * 4 + j], rs[m][j]);
    }
    if (lg == 0) {
        #pragma unroll
        for (int n = 0; n < 4; ++n)
            atomicAdd(&colp[n * 16 + lr], cs[n]);
    }
}

// ---------------- final reduce ----------------
__global__ __launch_bounds__(1024) void finalize_kernel(
    const float* __restrict__ rowsum, const float* __restrict__ colsum,
    const float* __restrict__ diag, float* __restrict__ out)
{
    float s = 0.f;
    for (int i = threadIdx.x; i < 3 * NB; i += 1024) {
        s += 0.5f * (logf(rowsum[i]) + logf(colsum[i])) + 10.0f - 10.0f * diag[i];
    }
    #pragma unroll
    for (int m = 32; m >= 1; m >>= 1) s += __shfl_xor(s, m);
    __shared__ float sw[16];
    if ((threadIdx.x & 63) == 0) sw[threadIdx.x >> 6] = s;
    __syncthreads();
    if (threadIdx.x == 0) {
        float t = 0.f;
        #pragma unroll
        for (int i = 0; i < 16; ++i) t += sw[i];
        out[0] = t * (1.0f / (3.0f * NB));
    }
}

extern "C" void kernel_launch(void* const* d_in, const int* in_sizes, int n_in,
                              void* d_out, int out_size, void* d_ws, size_t ws_size,
                              hipStream_t stream) {
    const float* z0 = (const float*)d_in[0];
    const float* z1 = (const float*)d_in[1];
    const float* z2 = (const float*)d_in[2];
    float* out = (float*)d_out;

    char* ws = (char*)d_ws;
    unsigned char* nrm8 = (unsigned char*)ws;               // 3*4096*512 fp8 = 6.3 MB
    const size_t nrm_bytes = (size_t)3 * NB * ND;
    float* rowsum = (float*)(ws + nrm_bytes);               // 3*4096 f32
    float* colsum = rowsum + 3 * NB;                        // 3*4096 f32
    float* diag = colsum + 3 * NB;                          // 3*4096 f32 (fully overwritten)

    nrm_kernel<<<dim3(NB / 4, 3), 256, 0, stream>>>(z0, z1, z2, nrm8, rowsum, colsum);
    pair_gemm_kernel<<<768, 512, 0, stream>>>(nrm8, rowsum, colsum, diag);
    finalize_kernel<<<1, 1024, 0, stream>>>(rowsum, colsum, diag, out);
}

// Round 7
// 75.962 us; speedup vs baseline: 1.4854x; 1.4854x over previous
//
#include <hip/hip_runtime.h>
#include <hip/hip_bf16.h>

#define NB 4096
#define ND 512

typedef int i32x4 __attribute__((ext_vector_type(4)));
typedef int i32x8 __attribute__((ext_vector_type(8)));
typedef float f32x4 __attribute__((ext_vector_type(4)));

#define AS1 __attribute__((address_space(1)))
#define AS3 __attribute__((address_space(3)))

// ---- f32 -> fp8 e4m3fn (OCP), RNE, |x| <= 1 ----
__device__ __forceinline__ unsigned int f2e4m3(float x) {
    float a = fabsf(x);
    unsigned s = (__float_as_uint(x) >> 24) & 0x80u;
    if (a < 0.015625f) {                       // denorm/zero: step 2^-9
        int q = __float2int_rn(a * 512.0f);    // 0..8 (8 -> 0x08 == 2^-6)
        return s | (unsigned)q;
    }
    unsigned u = __float_as_uint(a);
    u += 0x7FFFFu + ((u >> 20) & 1u);          // RNE to 3-bit mantissa
    unsigned e8 = (u >> 23) - 120u;            // 1..7 for a in [2^-6, 1]
    unsigned m = (u >> 20) & 7u;
    return s | (e8 << 3) | m;
}

// ---------------- normalize + cast to fp8 (wave per row) + zero-init sums ----------------
__global__ __launch_bounds__(256) void nrm_kernel(
    const float* __restrict__ z0, const float* __restrict__ z1,
    const float* __restrict__ z2, unsigned char* __restrict__ nrm8,
    float* __restrict__ rowsum, float* __restrict__ colsum)
{
    const int w = threadIdx.x >> 6, lane = threadIdx.x & 63;
    const int row = blockIdx.x * 4 + w;
    const int p = blockIdx.y;
    if (lane == 0) {
        rowsum[p * NB + row] = 0.f;
        colsum[p * NB + row] = 0.f;
    }
    const float* z = (p == 0) ? z0 : (p == 1) ? z1 : z2;
    const float4* zr = (const float4*)(z + (size_t)row * ND);
    const float4 a = zr[lane * 2], b = zr[lane * 2 + 1];
    float ss = a.x * a.x + a.y * a.y + a.z * a.z + a.w * a.w
             + b.x * b.x + b.y * b.y + b.z * b.z + b.w * b.w;
    #pragma unroll
    for (int m = 32; m >= 1; m >>= 1) ss += __shfl_xor(ss, m);
    const float inv = 1.0f / fmaxf(sqrtf(ss), 1e-8f);
    uint2 o;
    o.x = f2e4m3(a.x * inv) | (f2e4m3(a.y * inv) << 8)
        | (f2e4m3(a.z * inv) << 16) | (f2e4m3(a.w * inv) << 24);
    o.y = f2e4m3(b.x * inv) | (f2e4m3(b.y * inv) << 8)
        | (f2e4m3(b.z * inv) << 16) | (f2e4m3(b.w * inv) << 24);
    *(uint2*)(nrm8 + ((size_t)p * NB + row) * ND + lane * 8) = o;
}

// ---------------- fused pair GEMM, MX-fp8: 256x256 tile, BK=128, 8 waves ----------------
// Per-wave pipelined (reads -> stages -> MFMA cluster; compiler-counted lgkm),
// ONE vmcnt(4)+barrier per K-tile. LDS: A x3 + B x2 = 160 KB. unroll 1 to
// keep VGPR demand under the 128-VGPR half of the unified file (acc = 128 AGPR).
__global__ __launch_bounds__(512, 2) void pair_gemm_kernel(
    const unsigned char* __restrict__ nrm8,
    float* __restrict__ rowsum, float* __restrict__ colsum,
    float* __restrict__ diag)
{
    // XCD chunking: per pair, each XCD owns an 8by x 4bx chunk (WS < 4 MB L2)
    const int bid = blockIdx.x;
    const int xcd = bid & 7;
    const int rank = bid >> 3;
    const int p = rank >> 5;
    const int r2 = rank & 31;
    const int by = (xcd & 1) * 8 + (r2 >> 2);
    const int bx = (xcd >> 1) * 4 + (r2 & 3);
    const int ia = (p == 2) ? 1 : 0;
    const int ib = (p == 0) ? 1 : 2;

    const char* Aglob = (const char*)nrm8 + ((size_t)ia * NB + (size_t)by * 256) * ND;
    const char* Bglob = (const char*)nrm8 + ((size_t)ib * NB + (size_t)bx * 256) * ND;

    __shared__ char lds[163840];  // A: 3 x 32KB at 0; B: 2 x 32KB at 98304

    const int tid = threadIdx.x;
    const int lane = tid & 63;
    const int w = tid >> 6;
    const int wr = w >> 2, wc = w & 3;   // 2M x 4N; wave tile 128x64
    const int lr = lane & 15, lg = lane >> 4;

    // staging: op-tile = 256 rows x 128 B = 2048 chunks of 16B; 4 per thread.
    // row r = c>>3, phys slot qp = c&7 holds logical qp^(r&7) -> inverse-swizzled
    // SOURCE (rule 21), LDS dest linear. Source row stride = ND bytes.
    int srcOff[4];
    #pragma unroll
    for (int q = 0; q < 4; ++q) {
        const int c = q * 512 + tid;
        const int r = c >> 3;
        const int ql = (c & 7) ^ (r & 7);
        srcOff[q] = r * ND + ql * 16;
    }

    // frag reads: lane-group lg covers logical slots {2lg, 2lg+1}; phys = ^(lr&7).
    // Same map for A and B, so any HW-internal k permutation cancels.
    const int s0 = ((2 * lg) ^ (lr & 7)) * 16;
    const int s1 = ((2 * lg + 1) ^ (lr & 7)) * 16;
    const int arow = (wr * 128 + lr) * 128;
    const int brow = (wc * 64 + lr) * 128;

    f32x4 acc[8][4] = {};

    #define STAGE(gsrc, dstbase) do {                                               \
        _Pragma("unroll")                                                           \
        for (int q = 0; q < 4; ++q)                                                 \
            __builtin_amdgcn_global_load_lds(                                       \
                (const AS1 void*)((gsrc) + srcOff[q]),                              \
                (AS3 void*)(lds + (dstbase) + q * 8192 + w * 1024), 16, 0, 0);      \
    } while (0)

    #define LDF(dst, buf, rowbase, idx) do {                                        \
        i32x4 lo_ = *(const i32x4*)((buf) + (rowbase) + (idx) * 2048 + s0);         \
        i32x4 hi_ = *(const i32x4*)((buf) + (rowbase) + (idx) * 2048 + s1);         \
        dst = __builtin_shufflevector(lo_, hi_, 0, 1, 2, 3, 4, 5, 6, 7);            \
    } while (0)

    #define SC 0x7F7F7F7F

    // prologue: A(0)->abuf0, B(0)->bbuf0, A(1)->abuf1; drain A(0)+B(0)
    STAGE(Aglob, 0);
    STAGE(Bglob, 98304);
    STAGE(Aglob + 128, 32768);
    asm volatile("s_waitcnt vmcnt(4)" ::: "memory");
    __builtin_amdgcn_s_barrier();

    int abR = 0, abS = 65536;            // A read buf (t%3), A stage buf ((t+2)%3)
    int bbR = 98304, bbS = 131072;       // B read/stage (alternating)
    const char* AgS = Aglob + 256;       // A(t+2) source K-slice
    const char* BgS = Bglob + 128;       // B(t+1) source K-slice

    #pragma unroll 1
    for (int t = 0; t < 4; ++t) {
        const char* abuf = lds + abR;
        const char* bbuf = lds + bbR;

        i32x8 bfr[4], afA[4], afB[4];
        #pragma unroll
        for (int n = 0; n < 4; ++n) LDF(bfr[n], bbuf, brow, n);
        #pragma unroll
        for (int m = 0; m < 4; ++m) LDF(afA[m], abuf, arow, m);
        #pragma unroll
        for (int m = 0; m < 4; ++m) LDF(afB[m], abuf, arow, m + 4);

        if (t < 3) STAGE(BgS, bbS);
        if (t < 2) STAGE(AgS, abS);

        __builtin_amdgcn_s_setprio(1);
        #pragma unroll
        for (int m = 0; m < 4; ++m)
            #pragma unroll
            for (int n = 0; n < 4; ++n)
                acc[m][n] = __builtin_amdgcn_mfma_scale_f32_16x16x128_f8f6f4(
                    afA[m], bfr[n], acc[m][n], 0, 0, 0, SC, 0, SC);
        #pragma unroll
        for (int m = 0; m < 4; ++m)
            #pragma unroll
            for (int n = 0; n < 4; ++n)
                acc[m + 4][n] = __builtin_amdgcn_mfma_scale_f32_16x16x128_f8f6f4(
                    afB[m], bfr[n], acc[m + 4][n], 0, 0, 0, SC, 0, SC);
        __builtin_amdgcn_s_setprio(0);

        // gate: drain A(t+1)+B(t+1); leave A(t+2)'s 4 loads in flight
        if (t < 2)       asm volatile("s_waitcnt vmcnt(4)" ::: "memory");
        else if (t == 2) asm volatile("s_waitcnt vmcnt(0)" ::: "memory");
        if (t < 3) __builtin_amdgcn_s_barrier();

        abR += 32768; if (abR == 98304) abR = 0;
        abS += 32768; if (abS == 98304) abS = 0;
        const int tmp = bbR; bbR = bbS; bbS = tmp;
        AgS += 128; BgS += 128;
    }
    #undef STAGE
    #undef LDF

    // ---- diag (pre-exp): C frag row = lg*4+j (within 16), col = lr ----
    if (bx == by) {
        #pragma unroll
        for (int m = 0; m < 8; ++m)
            #pragma unroll
            for (int n = 0; n < 4; ++n)
                #pragma unroll
                for (int j = 0; j < 4; ++j) {
                    const int r = wr * 128 + m * 16 + lg * 4 + j;
                    const int c = wc * 64 + n * 16 + lr;
                    if (r == c) diag[p * NB + by * 256 + r] = acc[m][n][j];
                }
    }

    // ---- epilogue: e = exp2(sim*10*log2e - 10*log2e), row/col partials ----
    constexpr float C10 = 14.42695040888963f;
    float rs[8][4];
    float cs[4] = {0.f, 0.f, 0.f, 0.f};
    #pragma unroll
    for (int m = 0; m < 8; ++m)
        #pragma unroll
        for (int j = 0; j < 4; ++j) rs[m][j] = 0.f;

    #pragma unroll
    for (int m = 0; m < 8; ++m)
        #pragma unroll
        for (int n = 0; n < 4; ++n)
            #pragma unroll
            for (int j = 0; j < 4; ++j) {
                float e = exp2f(fmaf(acc[m][n][j], C10, -C10));
                rs[m][j] += e;
                cs[n] += e;
            }

    #pragma unroll
    for (int m = 0; m < 8; ++m)
        #pragma unroll
        for (int j = 0; j < 4; ++j) {
            float v = rs[m][j];
            v += __shfl_xor(v, 1);
            v += __shfl_xor(v, 2);
            v += __shfl_xor(v, 4);
            v += __shfl_xor(v, 8);
            rs[m][j] = v;
        }
    #pragma unroll
    for (int n = 0; n < 4; ++n) {
        float v = cs[n];
        v += __shfl_xor(v, 16);
        v += __shfl_xor(v, 32);
        cs[n] = v;
    }

    float* rowp = rowsum + p * NB + by * 256 + wr * 128;
    float* colp = colsum + p * NB + bx * 256 + wc * 64;
    if (lr == 0) {
        #pragma unroll
        for (int m = 0; m < 8; ++m)
            #pragma unroll
            for (int j = 0; j < 4; ++j)
                atomicAdd(&rowp[m * 16 + lg * 4 + j], rs[m][j]);
    }
    if (lg == 0) {
        #pragma unroll
        for (int n = 0; n < 4; ++n)
            atomicAdd(&colp[n * 16 + lr], cs[n]);
    }
}

// ---------------- final reduce ----------------
__global__ __launch_bounds__(1024) void finalize_kernel(
    const float* __restrict__ rowsum, const float* __restrict__ colsum,
    const float* __restrict__ diag, float* __restrict__ out)
{
    float s = 0.f;
    for (int i = threadIdx.x; i < 3 * NB; i += 1024) {
        s += 0.5f * (logf(rowsum[i]) + logf(colsum[i])) + 10.0f - 10.0f * diag[i];
    }
    #pragma unroll
    for (int m = 32; m >= 1; m >>= 1) s += __shfl_xor(s, m);
    __shared__ float sw[16];
    if ((threadIdx.x & 63) == 0) sw[threadIdx.x >> 6] = s;
    __syncthreads();
    if (threadIdx.x == 0) {
        float t = 0.f;
        #pragma unroll
        for (int i = 0; i < 16; ++i) t += sw[i];
        out[0] = t * (1.0f / (3.0f * NB));
    }
}

extern "C" void kernel_launch(void* const* d_in, const int* in_sizes, int n_in,
                              void* d_out, int out_size, void* d_ws, size_t ws_size,
                              hipStream_t stream) {
    const float* z0 = (const float*)d_in[0];
    const float* z1 = (const float*)d_in[1];
    const float* z2 = (const float*)d_in[2];
    float* out = (float*)d_out;

    char* ws = (char*)d_ws;
    unsigned char* nrm8 = (unsigned char*)ws;               // 3*4096*512 fp8 = 6.3 MB
    const size_t nrm_bytes = (size_t)3 * NB * ND;
    float* rowsum = (float*)(ws + nrm_bytes);               // 3*4096 f32
    float* colsum = rowsum + 3 * NB;                        // 3*4096 f32
    float* diag = colsum + 3 * NB;                          // 3*4096 f32 (fully overwritten)

    nrm_kernel<<<dim3(NB / 4, 3), 256, 0, stream>>>(z0, z1, z2, nrm8, rowsum, colsum);
    pair_gemm_kernel<<<768, 512, 0, stream>>>(nrm8, rowsum, colsum, diag);
    finalize_kernel<<<1, 1024, 0, stream>>>(rowsum, colsum, diag, out);
}